// Round 12
// baseline (706.360 us; speedup 1.0000x reference)
//
#include <hip/hip_runtime.h>

typedef __attribute__((ext_vector_type(8))) short bf16x8;   // 8 bf16 = 4 VGPRs
typedef __attribute__((ext_vector_type(4))) float f32x4;

#define MFMA16(A, B, C) __builtin_amdgcn_mfma_f32_16x16x32_bf16(A, B, C, 0, 0, 0)

__device__ __forceinline__ float4 ld4(const float* p) {
  return *reinterpret_cast<const float4*>(p);
}

__device__ __forceinline__ unsigned short f2bf(float f) {
  unsigned u = __float_as_uint(f);
  unsigned r = u + 0x7FFFu + ((u >> 16) & 1u);   // RNE
  return (unsigned short)(r >> 16);
}

__device__ __forceinline__ float bf2f(unsigned short b) {
  return __uint_as_float(((unsigned)b) << 16);
}
__device__ __forceinline__ float bflo(unsigned u) { return __uint_as_float(u << 16); }
__device__ __forceinline__ float bfhi(unsigned u) { return __uint_as_float(u & 0xFFFF0000u); }
__device__ __forceinline__ unsigned bfpack(float lo, float hi) {
  return (unsigned)f2bf(lo) | ((unsigned)f2bf(hi) << 16);
}

__device__ __forceinline__ bf16x8 cvt8(float4 a, float4 b) {
  bf16x8 v;
  v[0] = (short)f2bf(a.x); v[1] = (short)f2bf(a.y);
  v[2] = (short)f2bf(a.z); v[3] = (short)f2bf(a.w);
  v[4] = (short)f2bf(b.x); v[5] = (short)f2bf(b.y);
  v[6] = (short)f2bf(b.z); v[7] = (short)f2bf(b.w);
  return v;
}

// ---- build padded CSR (both directions), MAXDEG=64 ----
__global__ void __launch_bounds__(256) k_fill(
    const int* __restrict__ row, const int* __restrict__ col,
    int* __restrict__ deg_s, int* __restrict__ deg_r,
    int* __restrict__ lst_s, int* __restrict__ lst_r, int E) {
  int e = blockIdx.x * 256 + threadIdx.x;
  if (e >= E) return;
  int r = row[e], c = col[e];
  int s0 = atomicAdd(deg_s + r, 1);
  if (s0 < 64) lst_s[(size_t)r * 64 + s0] = e;
  int s1 = atomicAdd(deg_r + c, 1);
  if (s1 < 64) lst_r[(size_t)c * 64 + s1] = e;
}

// ---- precombine: Ms=Wn[:,64:128].W3, cs=.b3; Mr/cr for 128:192; pu/pun ----
__global__ void __launch_bounds__(128) k_precomb(
    const float* __restrict__ Wn, const float* __restrict__ W3, const float* __restrict__ b3,
    const float* __restrict__ We, const float* __restrict__ u_,
    float* __restrict__ Ms, float* __restrict__ cs,
    float* __restrict__ Mr, float* __restrict__ cr,
    float* __restrict__ pu, float* __restrict__ pun, int G) {
  int t = threadIdx.x;
  if (blockIdx.x < 8) {
    int dir = t >> 6, o = t & 63;
    const float* wrow = Wn + (size_t)o * 256 + 64 + 64 * dir;
    float* M  = dir ? Mr : Ms;
    float* cv = dir ? cr : cs;
    if (blockIdx.x == 0) {
      float cb = 0.f;
      for (int k = 0; k < 64; ++k) cb = fmaf(wrow[k], b3[k], cb);
      cv[o] = cb;
    }
    int c0 = blockIdx.x * 16;
    for (int c = c0; c < c0 + 16; ++c) {
      float m = 0.f;
      for (int k = 0; k < 64; ++k) m = fmaf(wrow[k], W3[k * 128 + c], m);
      M[(size_t)o * 128 + c] = m;
    }
  } else {
    const float* W = (blockIdx.x == 8) ? We : Wn;
    float* dst = (blockIdx.x == 8) ? pu : pun;
    int o = t & 63;
    const float* wr = W + (size_t)o * 256 + 192;
    for (int g = t >> 6; g < G; g += 2) {
      float a = 0.f;
      const float* uv = u_ + (size_t)g * 64;
      for (int k = 0; k < 64; ++k) a = fmaf(wr[k], uv[k], a);
      dst[(size_t)g * 64 + o] = a;
    }
  }
}

// ---- pack B matrices to bf16 MFMA-frag layout (one-time) ----
__global__ void __launch_bounds__(256) k_pack(
    const float* __restrict__ We, const float* __restrict__ W1, const float* __restrict__ Wn,
    const float* __restrict__ Ms, const float* __restrict__ Mr,
    unsigned short* __restrict__ BpP, unsigned short* __restrict__ BpN) {
  int idx = blockIdx.x * 256 + threadIdx.x;
  if (idx < 2048) {
    int lane = idx & 63, nt = (idx >> 6) & 15, ks = idx >> 10;
    int l15 = lane & 15, lg = lane >> 4;
    int c = nt * 16 + l15, a = c >> 6, o = c & 63;
    bf16x8 v;
    #pragma unroll
    for (int j = 0; j < 8; ++j) {
      int k = ks * 32 + lg * 8 + j;
      float f = (a == 0) ? We[o * 256 + 64 + k]
              : (a == 1) ? We[o * 256 + 128 + k]
              : (a == 2) ? W1[o * 192 + k]
                         : W1[o * 192 + 64 + k];
      v[j] = (short)f2bf(f);
    }
    *(bf16x8*)(BpP + (size_t)idx * 8) = v;
  } else if (idx < 2048 + 2560) {
    int i2 = idx - 2048;
    int lane = i2 & 63, nt = (i2 >> 6) & 3, ks = i2 >> 8;
    int l15 = lane & 15, lg = lane >> 4;
    int col = nt * 16 + l15;
    bf16x8 v;
    #pragma unroll
    for (int j = 0; j < 8; ++j) {
      int k = ks * 32 + lg * 8 + j;
      float f = (k < 64) ? Wn[col * 256 + k]
              : (k < 192) ? Ms[col * 128 + (k - 64)]
                          : Mr[col * 128 + (k - 192)];
      v[j] = (short)f2bf(f);
    }
    *(bf16x8*)(BpN + (size_t)i2 * 8) = v;
  }
}

// ---- nodepre via MFMA; outputs phq[n][o] = {pack(px1,px2), pack(hq,hkv)} + x_bf ----
__global__ void __launch_bounds__(256) k_nodepre5(
    const float* __restrict__ x, const unsigned short* __restrict__ BpP,
    uint2* __restrict__ phq, unsigned short* __restrict__ x_bf, int N) {
  __shared__ unsigned short lB[2048 * 8];   // 32KB
  const int tid = threadIdx.x;
  for (int i = tid; i < 2048; i += 256)
    *(uint4*)(lB + (size_t)i * 8) = *(const uint4*)(BpP + (size_t)i * 8);
  __syncthreads();
  const int lane = tid & 63, wid = tid >> 6, l15 = lane & 15, lg = lane >> 4;
  const int n0 = (blockIdx.x * 4 + wid) * 16;
  if (n0 >= N) return;
  int arow = n0 + l15; if (arow >= N) arow = N - 1;
  const float* src = x + (size_t)arow * 64 + lg * 8;
  bf16x8 A0 = cvt8(ld4(src), ld4(src + 4));
  bf16x8 A1 = cvt8(ld4(src + 32), ld4(src + 36));
  if (n0 + l15 < N) {
    *(bf16x8*)(x_bf + (size_t)(n0 + l15) * 64 + lg * 8) = A0;
    *(bf16x8*)(x_bf + (size_t)(n0 + l15) * 64 + 32 + lg * 8) = A1;
  }
  f32x4 acc[16];
  #pragma unroll
  for (int nt = 0; nt < 16; ++nt) {
    acc[nt] = (f32x4){0.f, 0.f, 0.f, 0.f};
    acc[nt] = MFMA16(A0, *(const bf16x8*)(lB + ((size_t)(0 * 16 + nt) * 64 + lane) * 8), acc[nt]);
    acc[nt] = MFMA16(A1, *(const bf16x8*)(lB + ((size_t)(1 * 16 + nt) * 64 + lane) * 8), acc[nt]);
  }
  // nt = a*4+q, a: 0=px1 1=px2 2=hq 3=hkv ; o = q*16+l15
  #pragma unroll
  for (int q = 0; q < 4; ++q) {
    const int o = q * 16 + l15;
    #pragma unroll
    for (int j = 0; j < 4; ++j) {
      int n = n0 + lg * 4 + j;
      if (n < N) {
        uint2 v;
        v.x = bfpack(acc[q][j],     acc[4 + q][j]);
        v.y = bfpack(acc[8 + q][j], acc[12 + q][j]);
        phq[(size_t)n * 64 + o] = v;
      }
    }
  }
}

// ---- MFMA fused edge MLP + attention logits: wave = 16 edges;
//      B-frags in block-shared LDS (frees ~64 VGPR -> 5 waves/SIMD) ----
__global__ void __launch_bounds__(256, 5) k_edgeattn6(
    const float* __restrict__ ea,
    const uint2* __restrict__ phq, const float* __restrict__ pu,
    const float* __restrict__ We, const float* __restrict__ be,
    const float* __restrict__ W1, const float* __restrict__ b1, const float* __restrict__ w2,
    const int* __restrict__ row, const int* __restrict__ col, const int* __restrict__ ebat,
    float* __restrict__ edge_out, unsigned short* __restrict__ en_bf,
    float* __restrict__ w_s, float* __restrict__ w_r, int E) {
  __shared__ unsigned short B1l[512 * 8];         // 8KB: i = ks*256 + nt*64 + lane
  __shared__ unsigned short B2l[512 * 8];         // 8KB
  __shared__ unsigned short enl_all[4][16 * 64];  // per-wave 2KB bf16 tile, swizzled
  const int tid = threadIdx.x, lane = tid & 63, wid = tid >> 6;
  const int l15 = lane & 15, lg = lane >> 4;

  // ---- one-time per-block: load B-frags into LDS ----
  for (int i = tid; i < 512; i += 256) {
    int li = i & 63, nt = (i >> 6) & 3, ks = i >> 8;
    int l15i = li & 15, lgi = li >> 4;
    const float* s1 = We + (size_t)(nt * 16 + l15i) * 256 + ks * 32 + lgi * 8;
    *(bf16x8*)(B1l + (size_t)i * 8) = cvt8(ld4(s1), ld4(s1 + 4));
    const float* s2 = W1 + (size_t)(nt * 16 + l15i) * 192 + 128 + ks * 32 + lgi * 8;
    *(bf16x8*)(B2l + (size_t)i * 8) = cvt8(ld4(s2), ld4(s2 + 4));
  }
  __syncthreads();

  float be_l[4], b1_l[4], w2_l[4];
  #pragma unroll
  for (int nt = 0; nt < 4; ++nt) {
    be_l[nt] = be[nt * 16 + l15];
    b1_l[nt] = b1[nt * 16 + l15];
    w2_l[nt] = w2[nt * 16 + l15];
  }
  unsigned short* enl = enl_all[wid];
  const int nwaves = gridDim.x * 4;
  const int step = nwaves * 16;
  const int swz_r = (l15 & 7) << 4;
  const int start = (blockIdx.x * 4 + wid) * 16;

  // prologue: load first tile's indices
  int rj[4], cj[4], gj[4];
  if (start < E) {
    if (start + 16 <= E) {
      int4 r4 = *(const int4*)(row + start + lg * 4);
      int4 c4 = *(const int4*)(col + start + lg * 4);
      int4 g4 = *(const int4*)(ebat + start + lg * 4);
      rj[0]=r4.x; rj[1]=r4.y; rj[2]=r4.z; rj[3]=r4.w;
      cj[0]=c4.x; cj[1]=c4.y; cj[2]=c4.z; cj[3]=c4.w;
      gj[0]=g4.x; gj[1]=g4.y; gj[2]=g4.z; gj[3]=g4.w;
    } else {
      #pragma unroll
      for (int j = 0; j < 4; ++j) {
        int ee = start + lg * 4 + j; if (ee >= E) ee = E - 1;
        rj[j] = row[ee]; cj[j] = col[ee]; gj[j] = ebat[ee];
      }
    }
  }

  for (int e0 = start; e0 < E; e0 += step) {
    // ---- merged gathers (uint2: px in .x, hqk in .y) + pu, issued first ----
    uint2 vr[4][4], vc[4][4];
    float puv[4][4];
    #pragma unroll
    for (int j = 0; j < 4; ++j) {
      #pragma unroll
      for (int nt = 0; nt < 4; ++nt) {
        const int o = nt * 16 + l15;
        vr[j][nt] = phq[(size_t)rj[j] * 64 + o];
        vc[j][nt] = phq[(size_t)cj[j] * 64 + o];
        puv[j][nt] = pu[(size_t)gj[j] * 64 + o];
      }
    }

    // ---- A1-frags from ea ----
    int erow = e0 + l15; if (erow >= E) erow = E - 1;
    const float* arow = ea + (size_t)erow * 64;
    bf16x8 A1[2];
    #pragma unroll
    for (int ks = 0; ks < 2; ++ks) {
      const float* s = arow + ks * 32 + lg * 8;
      A1[ks] = cvt8(ld4(s), ld4(s + 4));
    }

    // ---- prefetch next tile's indices ----
    int rn[4] = {0,0,0,0}, cn[4] = {0,0,0,0}, gn[4] = {0,0,0,0};
    const int e1 = e0 + step;
    if (e1 < E) {
      if (e1 + 16 <= E) {
        int4 r4 = *(const int4*)(row + e1 + lg * 4);
        int4 c4 = *(const int4*)(col + e1 + lg * 4);
        int4 g4 = *(const int4*)(ebat + e1 + lg * 4);
        rn[0]=r4.x; rn[1]=r4.y; rn[2]=r4.z; rn[3]=r4.w;
        cn[0]=c4.x; cn[1]=c4.y; cn[2]=c4.z; cn[3]=c4.w;
        gn[0]=g4.x; gn[1]=g4.y; gn[2]=g4.z; gn[3]=g4.w;
      } else {
        #pragma unroll
        for (int j = 0; j < 4; ++j) {
          int ee = e1 + lg * 4 + j; if (ee >= E) ee = E - 1;
          rn[j] = row[ee]; cn[j] = col[ee]; gn[j] = ebat[ee];
        }
      }
    }

    // ---- GEMM1 (B from LDS) ----
    f32x4 acc[4];
    #pragma unroll
    for (int nt = 0; nt < 4; ++nt) acc[nt] = (f32x4){0.f, 0.f, 0.f, 0.f};
    #pragma unroll
    for (int ks = 0; ks < 2; ++ks) {
      #pragma unroll
      for (int nt = 0; nt < 4; ++nt) {
        bf16x8 B = *(const bf16x8*)(B1l + ((size_t)(ks * 256 + nt * 64 + lane)) * 8);
        acc[nt] = MFMA16(A1[ks], B, acc[nt]);
      }
    }

    // ---- epilogue1: +bias +px1[r]+px2[c]+pu[g], relu, store f32+bf16, LDS pack ----
    #pragma unroll
    for (int j = 0; j < 4; ++j) {
      const int m = lg * 4 + j;
      const bool st = (e0 + m) < E;
      float* eo = edge_out + (size_t)(e0 + m) * 64 + l15;
      unsigned short* eb = en_bf + (size_t)(e0 + m) * 64 + l15;
      const int rbase = m * 128, sw = (m & 7) << 4;
      #pragma unroll
      for (int nt = 0; nt < 4; ++nt) {
        float v = acc[nt][j] + be_l[nt] + bflo(vr[j][nt].x) + bfhi(vc[j][nt].x) + puv[j][nt];
        v = fmaxf(v, 0.f);
        unsigned short bv = f2bf(v);
        if (st) { eo[nt * 16] = v; eb[nt * 16] = bv; }
        int byte = rbase + ((nt * 32 + l15 * 2) ^ sw);
        *(unsigned short*)((char*)enl + byte) = bv;
      }
    }

    // ---- A2-frags from LDS (swizzled read) ----
    asm volatile("s_waitcnt lgkmcnt(0)" ::: "memory");
    bf16x8 A2[2];
    #pragma unroll
    for (int ks = 0; ks < 2; ++ks) {
      int byte = l15 * 128 + (((ks * 64) + lg * 16) ^ swz_r);
      A2[ks] = *(const bf16x8*)((const char*)enl + byte);
    }

    // ---- GEMM2 (B from LDS) ----
    f32x4 tac[4];
    #pragma unroll
    for (int nt = 0; nt < 4; ++nt) tac[nt] = (f32x4){0.f, 0.f, 0.f, 0.f};
    #pragma unroll
    for (int ks = 0; ks < 2; ++ks) {
      #pragma unroll
      for (int nt = 0; nt < 4; ++nt) {
        bf16x8 B = *(const bf16x8*)(B2l + ((size_t)(ks * 256 + nt * 64 + lane)) * 8);
        tac[nt] = MFMA16(A2[ks], B, tac[nt]);
      }
    }

    // ---- epilogue2: logits from .y halves ----
    float as4[4] = {0.f, 0.f, 0.f, 0.f}, ar4[4] = {0.f, 0.f, 0.f, 0.f};
    #pragma unroll
    for (int j = 0; j < 4; ++j) {
      #pragma unroll
      for (int nt = 0; nt < 4; ++nt) {
        float tt = tac[nt][j] + b1_l[nt];
        float hs = tt + bflo(vr[j][nt].y) + bfhi(vc[j][nt].y); hs = (hs >= 0.f) ? hs : 0.01f * hs;
        float hr2 = tt + bflo(vc[j][nt].y) + bfhi(vr[j][nt].y); hr2 = (hr2 >= 0.f) ? hr2 : 0.01f * hr2;
        as4[j] = fmaf(hs, w2_l[nt], as4[j]);
        ar4[j] = fmaf(hr2, w2_l[nt], ar4[j]);
      }
    }
    #pragma unroll
    for (int j = 0; j < 4; ++j) {
      #pragma unroll
      for (int d = 1; d < 16; d <<= 1) {
        as4[j] += __shfl_xor(as4[j], d, 64);
        ar4[j] += __shfl_xor(ar4[j], d, 64);
      }
    }
    if (l15 == 0) {
      #pragma unroll
      for (int j = 0; j < 4; ++j) {
        int e = e0 + lg * 4 + j;
        if (e < E) { w_s[e] = as4[j]; w_r[e] = ar4[j]; }
      }
    }

    // ---- advance prefetched indices ----
    #pragma unroll
    for (int j = 0; j < 4; ++j) { rj[j] = rn[j]; cj[j] = cn[j]; gj[j] = gn[j]; }
  }
}

// ---- wave-per-node gather, BOTH directions via blockIdx.y; 8-deep pipeline ----
__global__ void __launch_bounds__(256) k_gatherw2(
    const unsigned short* __restrict__ x_bf, const unsigned short* __restrict__ en_bf,
    const float* __restrict__ w_s, const float* __restrict__ w_r,
    const int* __restrict__ lst_s, const int* __restrict__ lst_r,
    const int* __restrict__ deg_s, const int* __restrict__ deg_r,
    const int* __restrict__ row, const int* __restrict__ col,
    unsigned short* __restrict__ ss_s, unsigned short* __restrict__ ss_r,
    float* __restrict__ gam_s, float* __restrict__ gam_r, int N) {
  const int dir = blockIdx.y;
  const float* w = dir ? w_r : w_s;
  const int* lst = dir ? lst_r : lst_s;
  const int* deg_a = dir ? deg_r : deg_s;
  const int* other_idx = dir ? row : col;
  unsigned short* ss = dir ? ss_r : ss_s;
  float* gam = dir ? gam_r : gam_s;

  int wid = threadIdx.x >> 6, lane = threadIdx.x & 63;
  int n = blockIdx.x * 4 + wid;
  if (n >= N) return;
  int deg = deg_a[n];
  deg = deg < 64 ? deg : 64;
  unsigned short* ssd = ss + (size_t)n * 128;
  if (deg == 0) {
    ssd[lane] = 0; ssd[64 + lane] = 0;
    if (lane == 0) gam[n] = 0.f;
    return;
  }
  int e = 0, oe = 0;
  float wv = -1e30f;
  if (lane < deg) {
    e = lst[(size_t)n * 64 + lane];
    oe = other_idx[e];
    wv = w[e];
  }
  float m = wv;
  #pragma unroll
  for (int d = 32; d; d >>= 1) m = fmaxf(m, __shfl_xor(m, d, 64));
  float p = (lane < deg) ? __expf(wv - m) : 0.f;
  float S = p;
  #pragma unroll
  for (int d = 32; d; d >>= 1) S += __shfl_xor(S, d, 64);
  float sx4[4] = {0.f, 0.f, 0.f, 0.f};
  float se4[4] = {0.f, 0.f, 0.f, 0.f};
  int i = 0;
  for (; i + 8 <= deg; i += 8) {
    float pp[8]; int oo[8], ee[8];
    #pragma unroll
    for (int k = 0; k < 8; ++k) {
      pp[k] = __shfl(p, i + k, 64);
      oo[k] = __shfl(oe, i + k, 64);
      ee[k] = __shfl(e, i + k, 64);
    }
    float xv[8], ev[8];
    #pragma unroll
    for (int k = 0; k < 8; ++k) {
      xv[k] = bf2f(x_bf[(size_t)oo[k] * 64 + lane]);
      ev[k] = bf2f(en_bf[(size_t)ee[k] * 64 + lane]);
    }
    #pragma unroll
    for (int k = 0; k < 8; ++k) {
      sx4[k & 3] = fmaf(pp[k], xv[k], sx4[k & 3]);
      se4[k & 3] = fmaf(pp[k], ev[k], se4[k & 3]);
    }
  }
  for (; i + 4 <= deg; i += 4) {
    float pp[4]; int oo[4], ee[4];
    #pragma unroll
    for (int k = 0; k < 4; ++k) {
      pp[k] = __shfl(p, i + k, 64);
      oo[k] = __shfl(oe, i + k, 64);
      ee[k] = __shfl(e, i + k, 64);
    }
    #pragma unroll
    for (int k = 0; k < 4; ++k) {
      sx4[k] = fmaf(pp[k], bf2f(x_bf[(size_t)oo[k] * 64 + lane]), sx4[k]);
      se4[k] = fmaf(pp[k], bf2f(en_bf[(size_t)ee[k] * 64 + lane]), se4[k]);
    }
  }
  for (; i < deg; ++i) {
    float pi = __shfl(p, i, 64);
    int ei = __shfl(e, i, 64);
    int oi = __shfl(oe, i, 64);
    sx4[0] = fmaf(pi, bf2f(x_bf[(size_t)oi * 64 + lane]), sx4[0]);
    se4[0] = fmaf(pi, bf2f(en_bf[(size_t)ei * 64 + lane]), se4[0]);
  }
  float sx = (sx4[0] + sx4[1]) + (sx4[2] + sx4[3]);
  float se = (se4[0] + se4[1]) + (se4[2] + se4[3]);
  float inv = 1.f / (S + 1e-16f);
  ssd[lane] = f2bf(sx * inv);
  ssd[64 + lane] = f2bf(se * inv);
  if (lane == 0) gam[n] = S * inv;
}

// ---- node MLP via MFMA: A-rows read directly as bf16 (x_bf | ss_s | ss_r) ----
__global__ void __launch_bounds__(256) k_node4(
    const unsigned short* __restrict__ x_bf,
    const unsigned short* __restrict__ ss_s, const unsigned short* __restrict__ ss_r,
    const float* __restrict__ gam_s, const float* __restrict__ gam_r,
    const unsigned short* __restrict__ BpN,
    const float* __restrict__ bn, const float* __restrict__ cs, const float* __restrict__ cr,
    const float* __restrict__ pun, const int* __restrict__ nbat,
    float* __restrict__ x_out, int N) {
  __shared__ unsigned short lB[2560 * 8];   // 40KB
  const int tid = threadIdx.x;
  for (int i = tid; i < 2560; i += 256)
    *(uint4*)(lB + (size_t)i * 8) = *(const uint4*)(BpN + (size_t)i * 8);
  __syncthreads();
  const int lane = tid & 63, wid = tid >> 6, l15 = lane & 15, lg = lane >> 4;
  const int n0 = (blockIdx.x * 4 + wid) * 16;
  if (n0 >= N) return;
  int arow = n0 + l15; if (arow >= N) arow = N - 1;

  f32x4 acc[4];
  #pragma unroll
  for (int nt = 0; nt < 4; ++nt) acc[nt] = (f32x4){0.f, 0.f, 0.f, 0.f};

  #pragma unroll
  for (int ks = 0; ks < 10; ++ks) {
    const unsigned short* s;
    if (ks < 2)      s = x_bf + (size_t)arow * 64  + ks * 32 + lg * 8;
    else if (ks < 6) s = ss_s + (size_t)arow * 128 + (ks - 2) * 32 + lg * 8;
    else             s = ss_r + (size_t)arow * 128 + (ks - 6) * 32 + lg * 8;
    bf16x8 A = *(const bf16x8*)s;
    #pragma unroll
    for (int nt = 0; nt < 4; ++nt)
      acc[nt] = MFMA16(A, *(const bf16x8*)(lB + ((size_t)(ks * 4 + nt) * 64 + lane) * 8), acc[nt]);
  }

  #pragma unroll
  for (int j = 0; j < 4; ++j) {
    int n = n0 + lg * 4 + j;
    int nn = n < N ? n : N - 1;
    int g = nbat[nn];
    float gs = gam_s[nn], gr = gam_r[nn];
    #pragma unroll
    for (int nt = 0; nt < 4; ++nt) {
      int o = nt * 16 + l15;
      float v = acc[nt][j] + bn[o] + pun[(size_t)g * 64 + o] + gs * cs[o] + gr * cr[o];
      v = fmaxf(v, 0.f);
      if (n < N) x_out[(size_t)n * 64 + o] = v;
    }
  }
}

// ---- segment-sum f32 (sorted ids, run-length + atomic flush), CHUNK=64 ----
__global__ void __launch_bounds__(256) k_segsum(
    const float* __restrict__ vals, const int* __restrict__ seg,
    float* __restrict__ out, int n) {
  int d = threadIdx.x & 63;
  int grp = threadIdx.x >> 6;
  long base = (long)blockIdx.x * 256 + (long)grp * 64;
  float sum = 0.f;
  int cur = -1;
  for (int k = 0; k < 64; ++k) {
    long e = base + k;
    if (e >= n) break;
    int gb = seg[e];
    float v = vals[e * 64 + d];
    if (gb != cur) {
      if (cur >= 0) atomicAdd(out + (size_t)cur * 64 + d, sum);
      cur = gb; sum = v;
    } else {
      sum += v;
    }
  }
  if (cur >= 0) atomicAdd(out + (size_t)cur * 64 + d, sum);
}

// ---- segment-sum bf16 input, CHUNK=64 ----
__global__ void __launch_bounds__(256) k_segsum_bf(
    const unsigned short* __restrict__ vals, const int* __restrict__ seg,
    float* __restrict__ out, int n) {
  int d = threadIdx.x & 63;
  int grp = threadIdx.x >> 6;
  long base = (long)blockIdx.x * 256 + (long)grp * 64;
  float sum = 0.f;
  int cur = -1;
  for (int k = 0; k < 64; ++k) {
    long e = base + k;
    if (e >= n) break;
    int gb = seg[e];
    float v = bf2f(vals[e * 64 + d]);
    if (gb != cur) {
      if (cur >= 0) atomicAdd(out + (size_t)cur * 64 + d, sum);
      cur = gb; sum = v;
    } else {
      sum += v;
    }
  }
  if (cur >= 0) atomicAdd(out + (size_t)cur * 64 + d, sum);
}

// ---- global MLP ----
__global__ void __launch_bounds__(64) k_glob(
    const float* __restrict__ u, const float* __restrict__ nagg, const float* __restrict__ eagg,
    const float* __restrict__ Wg, const float* __restrict__ bg,
    float* __restrict__ u_out, int G) {
  int t = blockIdx.x * 64 + threadIdx.x;
  if (t >= G * 64) return;
  int g = t >> 6, o = t & 63;
  float acc = bg[o];
  const float* wr = Wg + (size_t)o * 192;
  for (int i = 0; i < 64; ++i) acc = fmaf(u[g * 64 + i],    wr[i],       acc);
  for (int i = 0; i < 64; ++i) acc = fmaf(nagg[g * 64 + i], wr[64 + i],  acc);
  for (int i = 0; i < 64; ++i) acc = fmaf(eagg[g * 64 + i], wr[128 + i], acc);
  u_out[t] = fmaxf(acc, 0.f);
}

extern "C" void kernel_launch(void* const* d_in, const int* in_sizes, int n_in,
                              void* d_out, int out_size, void* d_ws, size_t ws_size,
                              hipStream_t stream) {
  const float* x   = (const float*)d_in[0];
  const float* ea  = (const float*)d_in[1];
  const float* u   = (const float*)d_in[2];
  const float* We  = (const float*)d_in[3];
  const float* be  = (const float*)d_in[4];
  const float* Wn  = (const float*)d_in[5];
  const float* bn  = (const float*)d_in[6];
  const float* Wg  = (const float*)d_in[7];
  const float* bg  = (const float*)d_in[8];
  const float* W1  = (const float*)d_in[9];
  const float* b1  = (const float*)d_in[10];
  const float* w2  = (const float*)d_in[11];
  const float* W3  = (const float*)d_in[12];
  const float* b3  = (const float*)d_in[13];
  const int* eidx  = (const int*)d_in[14];
  const int* nbat  = (const int*)d_in[15];
  const int* ebat  = (const int*)d_in[16];

  const int N = in_sizes[0] / 64;
  const int E = in_sizes[1] / 64;
  const int G = in_sizes[2] / 64;
  const int* row = eidx;
  const int* col = eidx + E;

  float* out   = (float*)d_out;
  float* x_out = out;
  float* e_out = out + (size_t)N * 64;
  float* u_out = out + (size_t)(N + E) * 64;

  // ---- workspace layout (float units) ----
  float* ws = (float*)d_ws;
  uint2* phq = (uint2*)ws;                                   // N*64 uint2 (= N*128 floats)
  // after k_edgeattn6, phq region is dead -> reuse for bf16 ss arrays
  unsigned short* ss_s = (unsigned short*)ws;                // N*128 ushort
  unsigned short* ss_r = (unsigned short*)(ws + (size_t)N * 64);  // N*128 ushort
  unsigned short* x_bf = (unsigned short*)(ws + (size_t)N * 128); // N*64 ushort
  float* w_s = (float*)(x_bf + (size_t)N * 64);              // E
  float* w_r = w_s + E;                                      // E
  float* pu  = w_r + E;                                      // G*64
  float* pun = pu + (size_t)G * 64;                          // G*64
  int* lst_s = (int*)(pun + (size_t)G * 64);                 // N*64
  int* lst_r = lst_s + (size_t)N * 64;                       // N*64
  int* deg_s = lst_r + (size_t)N * 64;                       // N   (memset from here...)
  int* deg_r = deg_s + N;                                    // N
  float* nagg = (float*)(deg_r + N);                         // G*64
  float* eagg = nagg + (size_t)G * 64;                       // G*64 (...to here)
  float* gam_s = eagg + (size_t)G * 64;                      // N
  float* gam_r = gam_s + N;                                  // N
  float* Ms = gam_r + N;                                     // 64*128
  float* Mr = Ms + 64 * 128;                                 // 64*128
  float* cs = Mr + 64 * 128;                                 // 64
  float* cr = cs + 64;                                       // 64
  unsigned short* BpP = (unsigned short*)(cr + 64);          // 2048*8 ushort
  unsigned short* BpN = BpP + 2048 * 8;                      // 2560*8 ushort
  unsigned short* en_bf = BpN + 2560 * 8;                    // E*64 ushort

  hipMemsetAsync(deg_s, 0, (2 * (size_t)N + 2 * (size_t)G * 64) * sizeof(int), stream);

  const int gE = (E + 255) / 256;
  const int gT = (N / 16 + 3) / 4;   // MFMA node-tile blocks (4 waves x 16 nodes)

  k_fill<<<gE, 256, 0, stream>>>(row, col, deg_s, deg_r, lst_s, lst_r, E);
  k_precomb<<<10, 128, 0, stream>>>(Wn, W3, b3, We, u, Ms, cs, Mr, cr, pu, pun, G);
  k_pack<<<18, 256, 0, stream>>>(We, W1, Wn, Ms, Mr, BpP, BpN);
  k_nodepre5<<<gT, 256, 0, stream>>>(x, BpP, phq, x_bf, N);
  k_edgeattn6<<<1280, 256, 0, stream>>>(ea, phq, pu, We, be, W1, b1, w2,
                                        row, col, ebat, e_out, en_bf, w_s, w_r, E);
  k_segsum_bf<<<(E + 255) / 256, 256, 0, stream>>>(en_bf, ebat, eagg, E);
  // gather overwrites phq region (dead after k_edgeattn6)
  k_gatherw2<<<dim3((N + 3) / 4, 2), 256, 0, stream>>>(
      x_bf, en_bf, w_s, w_r, lst_s, lst_r, deg_s, deg_r, row, col,
      ss_s, ss_r, gam_s, gam_r, N);
  k_node4<<<gT, 256, 0, stream>>>(x_bf, ss_s, ss_r, gam_s, gam_r, BpN, bn, cs, cr,
                                  pun, nbat, x_out, N);
  k_segsum<<<(N + 255) / 256, 256, 0, stream>>>(x_out, nbat, nagg, N);
  k_glob<<<(G * 64 + 63) / 64, 64, 0, stream>>>(u, nagg, eagg, Wg, bg, u_out, G);
}

// Round 13
// 460.974 us; speedup vs baseline: 1.5323x; 1.5323x over previous
//
#include <hip/hip_runtime.h>

typedef __attribute__((ext_vector_type(8))) short bf16x8;   // 8 bf16 = 4 VGPRs
typedef __attribute__((ext_vector_type(4))) float f32x4;

#define MFMA16(A, B, C) __builtin_amdgcn_mfma_f32_16x16x32_bf16(A, B, C, 0, 0, 0)

__device__ __forceinline__ float4 ld4(const float* p) {
  return *reinterpret_cast<const float4*>(p);
}

__device__ __forceinline__ unsigned short f2bf(float f) {
  unsigned u = __float_as_uint(f);
  unsigned r = u + 0x7FFFu + ((u >> 16) & 1u);   // RNE
  return (unsigned short)(r >> 16);
}

__device__ __forceinline__ float bf2f(unsigned short b) {
  return __uint_as_float(((unsigned)b) << 16);
}
__device__ __forceinline__ float bflo(unsigned u) { return __uint_as_float(u << 16); }
__device__ __forceinline__ float bfhi(unsigned u) { return __uint_as_float(u & 0xFFFF0000u); }
__device__ __forceinline__ unsigned bfpack(float lo, float hi) {
  return (unsigned)f2bf(lo) | ((unsigned)f2bf(hi) << 16);
}

__device__ __forceinline__ bf16x8 cvt8(float4 a, float4 b) {
  bf16x8 v;
  v[0] = (short)f2bf(a.x); v[1] = (short)f2bf(a.y);
  v[2] = (short)f2bf(a.z); v[3] = (short)f2bf(a.w);
  v[4] = (short)f2bf(b.x); v[5] = (short)f2bf(b.y);
  v[6] = (short)f2bf(b.z); v[7] = (short)f2bf(b.w);
  return v;
}

// ---- build padded CSR (both directions), MAXDEG=64 ----
__global__ void __launch_bounds__(256) k_fill(
    const int* __restrict__ row, const int* __restrict__ col,
    int* __restrict__ deg_s, int* __restrict__ deg_r,
    int* __restrict__ lst_s, int* __restrict__ lst_r, int E) {
  int e = blockIdx.x * 256 + threadIdx.x;
  if (e >= E) return;
  int r = row[e], c = col[e];
  int s0 = atomicAdd(deg_s + r, 1);
  if (s0 < 64) lst_s[(size_t)r * 64 + s0] = e;
  int s1 = atomicAdd(deg_r + c, 1);
  if (s1 < 64) lst_r[(size_t)c * 64 + s1] = e;
}

// ---- precombine: Ms=Wn[:,64:128].W3, cs=.b3; Mr/cr for 128:192; pu/pun ----
__global__ void __launch_bounds__(128) k_precomb(
    const float* __restrict__ Wn, const float* __restrict__ W3, const float* __restrict__ b3,
    const float* __restrict__ We, const float* __restrict__ u_,
    float* __restrict__ Ms, float* __restrict__ cs,
    float* __restrict__ Mr, float* __restrict__ cr,
    float* __restrict__ pu, float* __restrict__ pun, int G) {
  int t = threadIdx.x;
  if (blockIdx.x < 8) {
    int dir = t >> 6, o = t & 63;
    const float* wrow = Wn + (size_t)o * 256 + 64 + 64 * dir;
    float* M  = dir ? Mr : Ms;
    float* cv = dir ? cr : cs;
    if (blockIdx.x == 0) {
      float cb = 0.f;
      for (int k = 0; k < 64; ++k) cb = fmaf(wrow[k], b3[k], cb);
      cv[o] = cb;
    }
    int c0 = blockIdx.x * 16;
    for (int c = c0; c < c0 + 16; ++c) {
      float m = 0.f;
      for (int k = 0; k < 64; ++k) m = fmaf(wrow[k], W3[k * 128 + c], m);
      M[(size_t)o * 128 + c] = m;
    }
  } else {
    const float* W = (blockIdx.x == 8) ? We : Wn;
    float* dst = (blockIdx.x == 8) ? pu : pun;
    int o = t & 63;
    const float* wr = W + (size_t)o * 256 + 192;
    for (int g = t >> 6; g < G; g += 2) {
      float a = 0.f;
      const float* uv = u_ + (size_t)g * 64;
      for (int k = 0; k < 64; ++k) a = fmaf(wr[k], uv[k], a);
      dst[(size_t)g * 64 + o] = a;
    }
  }
}

// ---- pack B matrices to bf16 MFMA-frag layout (one-time) ----
__global__ void __launch_bounds__(256) k_pack(
    const float* __restrict__ We, const float* __restrict__ W1, const float* __restrict__ Wn,
    const float* __restrict__ Ms, const float* __restrict__ Mr,
    unsigned short* __restrict__ BpP, unsigned short* __restrict__ BpN) {
  int idx = blockIdx.x * 256 + threadIdx.x;
  if (idx < 2048) {
    int lane = idx & 63, nt = (idx >> 6) & 15, ks = idx >> 10;
    int l15 = lane & 15, lg = lane >> 4;
    int c = nt * 16 + l15, a = c >> 6, o = c & 63;
    bf16x8 v;
    #pragma unroll
    for (int j = 0; j < 8; ++j) {
      int k = ks * 32 + lg * 8 + j;
      float f = (a == 0) ? We[o * 256 + 64 + k]
              : (a == 1) ? We[o * 256 + 128 + k]
              : (a == 2) ? W1[o * 192 + k]
                         : W1[o * 192 + 64 + k];
      v[j] = (short)f2bf(f);
    }
    *(bf16x8*)(BpP + (size_t)idx * 8) = v;
  } else if (idx < 2048 + 2560) {
    int i2 = idx - 2048;
    int lane = i2 & 63, nt = (i2 >> 6) & 3, ks = i2 >> 8;
    int l15 = lane & 15, lg = lane >> 4;
    int col = nt * 16 + l15;
    bf16x8 v;
    #pragma unroll
    for (int j = 0; j < 8; ++j) {
      int k = ks * 32 + lg * 8 + j;
      float f = (k < 64) ? Wn[col * 256 + k]
              : (k < 192) ? Ms[col * 128 + (k - 64)]
                          : Mr[col * 128 + (k - 192)];
      v[j] = (short)f2bf(f);
    }
    *(bf16x8*)(BpN + (size_t)i2 * 8) = v;
  }
}

// ---- nodepre via MFMA; outputs phq[n][o] = {pack(px1,px2), pack(hq,hkv)} + x_bf ----
__global__ void __launch_bounds__(256) k_nodepre5(
    const float* __restrict__ x, const unsigned short* __restrict__ BpP,
    uint2* __restrict__ phq, unsigned short* __restrict__ x_bf, int N) {
  __shared__ unsigned short lB[2048 * 8];   // 32KB
  const int tid = threadIdx.x;
  for (int i = tid; i < 2048; i += 256)
    *(uint4*)(lB + (size_t)i * 8) = *(const uint4*)(BpP + (size_t)i * 8);
  __syncthreads();
  const int lane = tid & 63, wid = tid >> 6, l15 = lane & 15, lg = lane >> 4;
  const int n0 = (blockIdx.x * 4 + wid) * 16;
  if (n0 >= N) return;
  int arow = n0 + l15; if (arow >= N) arow = N - 1;
  const float* src = x + (size_t)arow * 64 + lg * 8;
  bf16x8 A0 = cvt8(ld4(src), ld4(src + 4));
  bf16x8 A1 = cvt8(ld4(src + 32), ld4(src + 36));
  if (n0 + l15 < N) {
    *(bf16x8*)(x_bf + (size_t)(n0 + l15) * 64 + lg * 8) = A0;
    *(bf16x8*)(x_bf + (size_t)(n0 + l15) * 64 + 32 + lg * 8) = A1;
  }
  f32x4 acc[16];
  #pragma unroll
  for (int nt = 0; nt < 16; ++nt) {
    acc[nt] = (f32x4){0.f, 0.f, 0.f, 0.f};
    acc[nt] = MFMA16(A0, *(const bf16x8*)(lB + ((size_t)(0 * 16 + nt) * 64 + lane) * 8), acc[nt]);
    acc[nt] = MFMA16(A1, *(const bf16x8*)(lB + ((size_t)(1 * 16 + nt) * 64 + lane) * 8), acc[nt]);
  }
  // nt = a*4+q, a: 0=px1 1=px2 2=hq 3=hkv ; o = q*16+l15
  #pragma unroll
  for (int q = 0; q < 4; ++q) {
    const int o = q * 16 + l15;
    #pragma unroll
    for (int j = 0; j < 4; ++j) {
      int n = n0 + lg * 4 + j;
      if (n < N) {
        uint2 v;
        v.x = bfpack(acc[q][j],     acc[4 + q][j]);
        v.y = bfpack(acc[8 + q][j], acc[12 + q][j]);
        phq[(size_t)n * 64 + o] = v;
      }
    }
  }
}

// ---- MFMA fused edge MLP + attention logits: wave = 16 edges;
//      merged uint2 gathers + next-tile index prefetch (best measured: 167us) ----
__global__ void __launch_bounds__(256, 2) k_edgeattn5(
    const float* __restrict__ ea,
    const uint2* __restrict__ phq, const float* __restrict__ pu,
    const float* __restrict__ We, const float* __restrict__ be,
    const float* __restrict__ W1, const float* __restrict__ b1, const float* __restrict__ w2,
    const int* __restrict__ row, const int* __restrict__ col, const int* __restrict__ ebat,
    float* __restrict__ edge_out, unsigned short* __restrict__ en_bf,
    float* __restrict__ w_s, float* __restrict__ w_r, int E) {
  __shared__ unsigned short enl_all[4][16 * 64];  // per-wave 2KB bf16 tile, swizzled
  const int tid = threadIdx.x, lane = tid & 63, wid = tid >> 6;
  const int l15 = lane & 15, lg = lane >> 4;

  bf16x8 B1[4][2], B2[4][2];
  #pragma unroll
  for (int nt = 0; nt < 4; ++nt) {
    #pragma unroll
    for (int ks = 0; ks < 2; ++ks) {
      const float* s1 = We + (size_t)(nt * 16 + l15) * 256 + ks * 32 + lg * 8;
      B1[nt][ks] = cvt8(ld4(s1), ld4(s1 + 4));
      const float* s2 = W1 + (size_t)(nt * 16 + l15) * 192 + 128 + ks * 32 + lg * 8;
      B2[nt][ks] = cvt8(ld4(s2), ld4(s2 + 4));
    }
  }
  float be_l[4], b1_l[4], w2_l[4];
  #pragma unroll
  for (int nt = 0; nt < 4; ++nt) {
    be_l[nt] = be[nt * 16 + l15];
    b1_l[nt] = b1[nt * 16 + l15];
    w2_l[nt] = w2[nt * 16 + l15];
  }
  unsigned short* enl = enl_all[wid];
  const int nwaves = gridDim.x * 4;
  const int step = nwaves * 16;
  const int swz_r = (l15 & 7) << 4;
  const int start = (blockIdx.x * 4 + wid) * 16;

  // prologue: load first tile's indices
  int rj[4], cj[4], gj[4];
  if (start < E) {
    if (start + 16 <= E) {
      int4 r4 = *(const int4*)(row + start + lg * 4);
      int4 c4 = *(const int4*)(col + start + lg * 4);
      int4 g4 = *(const int4*)(ebat + start + lg * 4);
      rj[0]=r4.x; rj[1]=r4.y; rj[2]=r4.z; rj[3]=r4.w;
      cj[0]=c4.x; cj[1]=c4.y; cj[2]=c4.z; cj[3]=c4.w;
      gj[0]=g4.x; gj[1]=g4.y; gj[2]=g4.z; gj[3]=g4.w;
    } else {
      #pragma unroll
      for (int j = 0; j < 4; ++j) {
        int ee = start + lg * 4 + j; if (ee >= E) ee = E - 1;
        rj[j] = row[ee]; cj[j] = col[ee]; gj[j] = ebat[ee];
      }
    }
  }

  for (int e0 = start; e0 < E; e0 += step) {
    // ---- merged gathers (uint2: px in .x, hqk in .y) + pu, issued first ----
    uint2 vr[4][4], vc[4][4];
    float puv[4][4];
    #pragma unroll
    for (int j = 0; j < 4; ++j) {
      #pragma unroll
      for (int nt = 0; nt < 4; ++nt) {
        const int o = nt * 16 + l15;
        vr[j][nt] = phq[(size_t)rj[j] * 64 + o];
        vc[j][nt] = phq[(size_t)cj[j] * 64 + o];
        puv[j][nt] = pu[(size_t)gj[j] * 64 + o];
      }
    }

    // ---- A1-frags from ea ----
    int erow = e0 + l15; if (erow >= E) erow = E - 1;
    const float* arow = ea + (size_t)erow * 64;
    bf16x8 A1[2];
    #pragma unroll
    for (int ks = 0; ks < 2; ++ks) {
      const float* s = arow + ks * 32 + lg * 8;
      A1[ks] = cvt8(ld4(s), ld4(s + 4));
    }

    // ---- prefetch next tile's indices ----
    int rn[4] = {0,0,0,0}, cn[4] = {0,0,0,0}, gn[4] = {0,0,0,0};
    const int e1 = e0 + step;
    if (e1 < E) {
      if (e1 + 16 <= E) {
        int4 r4 = *(const int4*)(row + e1 + lg * 4);
        int4 c4 = *(const int4*)(col + e1 + lg * 4);
        int4 g4 = *(const int4*)(ebat + e1 + lg * 4);
        rn[0]=r4.x; rn[1]=r4.y; rn[2]=r4.z; rn[3]=r4.w;
        cn[0]=c4.x; cn[1]=c4.y; cn[2]=c4.z; cn[3]=c4.w;
        gn[0]=g4.x; gn[1]=g4.y; gn[2]=g4.z; gn[3]=g4.w;
      } else {
        #pragma unroll
        for (int j = 0; j < 4; ++j) {
          int ee = e1 + lg * 4 + j; if (ee >= E) ee = E - 1;
          rn[j] = row[ee]; cn[j] = col[ee]; gn[j] = ebat[ee];
        }
      }
    }

    // ---- GEMM1 ----
    f32x4 acc[4];
    #pragma unroll
    for (int nt = 0; nt < 4; ++nt) acc[nt] = (f32x4){0.f, 0.f, 0.f, 0.f};
    #pragma unroll
    for (int nt = 0; nt < 4; ++nt) {
      acc[nt] = MFMA16(A1[0], B1[nt][0], acc[nt]);
      acc[nt] = MFMA16(A1[1], B1[nt][1], acc[nt]);
    }

    // ---- epilogue1: +bias +px1[r]+px2[c]+pu[g], relu, store f32+bf16, LDS pack ----
    #pragma unroll
    for (int j = 0; j < 4; ++j) {
      const int m = lg * 4 + j;
      const bool st = (e0 + m) < E;
      float* eo = edge_out + (size_t)(e0 + m) * 64 + l15;
      unsigned short* eb = en_bf + (size_t)(e0 + m) * 64 + l15;
      const int rbase = m * 128, sw = (m & 7) << 4;
      #pragma unroll
      for (int nt = 0; nt < 4; ++nt) {
        float v = acc[nt][j] + be_l[nt] + bflo(vr[j][nt].x) + bfhi(vc[j][nt].x) + puv[j][nt];
        v = fmaxf(v, 0.f);
        unsigned short bv = f2bf(v);
        if (st) { eo[nt * 16] = v; eb[nt * 16] = bv; }
        int byte = rbase + ((nt * 32 + l15 * 2) ^ sw);
        *(unsigned short*)((char*)enl + byte) = bv;
      }
    }

    // ---- A2-frags from LDS (swizzled read) ----
    asm volatile("s_waitcnt lgkmcnt(0)" ::: "memory");
    bf16x8 A2[2];
    #pragma unroll
    for (int ks = 0; ks < 2; ++ks) {
      int byte = l15 * 128 + (((ks * 64) + lg * 16) ^ swz_r);
      A2[ks] = *(const bf16x8*)((const char*)enl + byte);
    }

    // ---- GEMM2 ----
    f32x4 tac[4];
    #pragma unroll
    for (int nt = 0; nt < 4; ++nt) tac[nt] = (f32x4){0.f, 0.f, 0.f, 0.f};
    #pragma unroll
    for (int nt = 0; nt < 4; ++nt) {
      tac[nt] = MFMA16(A2[0], B2[nt][0], tac[nt]);
      tac[nt] = MFMA16(A2[1], B2[nt][1], tac[nt]);
    }

    // ---- epilogue2: logits from .y halves ----
    float as4[4] = {0.f, 0.f, 0.f, 0.f}, ar4[4] = {0.f, 0.f, 0.f, 0.f};
    #pragma unroll
    for (int j = 0; j < 4; ++j) {
      #pragma unroll
      for (int nt = 0; nt < 4; ++nt) {
        float tt = tac[nt][j] + b1_l[nt];
        float hs = tt + bflo(vr[j][nt].y) + bfhi(vc[j][nt].y); hs = (hs >= 0.f) ? hs : 0.01f * hs;
        float hr2 = tt + bflo(vc[j][nt].y) + bfhi(vr[j][nt].y); hr2 = (hr2 >= 0.f) ? hr2 : 0.01f * hr2;
        as4[j] = fmaf(hs, w2_l[nt], as4[j]);
        ar4[j] = fmaf(hr2, w2_l[nt], ar4[j]);
      }
    }
    #pragma unroll
    for (int j = 0; j < 4; ++j) {
      #pragma unroll
      for (int d = 1; d < 16; d <<= 1) {
        as4[j] += __shfl_xor(as4[j], d, 64);
        ar4[j] += __shfl_xor(ar4[j], d, 64);
      }
    }
    if (l15 == 0) {
      #pragma unroll
      for (int j = 0; j < 4; ++j) {
        int e = e0 + lg * 4 + j;
        if (e < E) { w_s[e] = as4[j]; w_r[e] = ar4[j]; }
      }
    }

    // ---- advance prefetched indices ----
    #pragma unroll
    for (int j = 0; j < 4; ++j) { rj[j] = rn[j]; cj[j] = cn[j]; gj[j] = gn[j]; }
  }
}

// ---- wave-per-node gather, BOTH directions via blockIdx.y; 8-deep pipeline ----
__global__ void __launch_bounds__(256) k_gatherw2(
    const unsigned short* __restrict__ x_bf, const unsigned short* __restrict__ en_bf,
    const float* __restrict__ w_s, const float* __restrict__ w_r,
    const int* __restrict__ lst_s, const int* __restrict__ lst_r,
    const int* __restrict__ deg_s, const int* __restrict__ deg_r,
    const int* __restrict__ row, const int* __restrict__ col,
    unsigned short* __restrict__ ss_s, unsigned short* __restrict__ ss_r,
    float* __restrict__ gam_s, float* __restrict__ gam_r, int N) {
  const int dir = blockIdx.y;
  const float* w = dir ? w_r : w_s;
  const int* lst = dir ? lst_r : lst_s;
  const int* deg_a = dir ? deg_r : deg_s;
  const int* other_idx = dir ? row : col;
  unsigned short* ss = dir ? ss_r : ss_s;
  float* gam = dir ? gam_r : gam_s;

  int wid = threadIdx.x >> 6, lane = threadIdx.x & 63;
  int n = blockIdx.x * 4 + wid;
  if (n >= N) return;
  int deg = deg_a[n];
  deg = deg < 64 ? deg : 64;
  unsigned short* ssd = ss + (size_t)n * 128;
  if (deg == 0) {
    ssd[lane] = 0; ssd[64 + lane] = 0;
    if (lane == 0) gam[n] = 0.f;
    return;
  }
  int e = 0, oe = 0;
  float wv = -1e30f;
  if (lane < deg) {
    e = lst[(size_t)n * 64 + lane];
    oe = other_idx[e];
    wv = w[e];
  }
  float m = wv;
  #pragma unroll
  for (int d = 32; d; d >>= 1) m = fmaxf(m, __shfl_xor(m, d, 64));
  float p = (lane < deg) ? __expf(wv - m) : 0.f;
  float S = p;
  #pragma unroll
  for (int d = 32; d; d >>= 1) S += __shfl_xor(S, d, 64);
  float sx4[4] = {0.f, 0.f, 0.f, 0.f};
  float se4[4] = {0.f, 0.f, 0.f, 0.f};
  int i = 0;
  for (; i + 8 <= deg; i += 8) {
    float pp[8]; int oo[8], ee[8];
    #pragma unroll
    for (int k = 0; k < 8; ++k) {
      pp[k] = __shfl(p, i + k, 64);
      oo[k] = __shfl(oe, i + k, 64);
      ee[k] = __shfl(e, i + k, 64);
    }
    float xv[8], ev[8];
    #pragma unroll
    for (int k = 0; k < 8; ++k) {
      xv[k] = bf2f(x_bf[(size_t)oo[k] * 64 + lane]);
      ev[k] = bf2f(en_bf[(size_t)ee[k] * 64 + lane]);
    }
    #pragma unroll
    for (int k = 0; k < 8; ++k) {
      sx4[k & 3] = fmaf(pp[k], xv[k], sx4[k & 3]);
      se4[k & 3] = fmaf(pp[k], ev[k], se4[k & 3]);
    }
  }
  for (; i + 4 <= deg; i += 4) {
    float pp[4]; int oo[4], ee[4];
    #pragma unroll
    for (int k = 0; k < 4; ++k) {
      pp[k] = __shfl(p, i + k, 64);
      oo[k] = __shfl(oe, i + k, 64);
      ee[k] = __shfl(e, i + k, 64);
    }
    #pragma unroll
    for (int k = 0; k < 4; ++k) {
      sx4[k] = fmaf(pp[k], bf2f(x_bf[(size_t)oo[k] * 64 + lane]), sx4[k]);
      se4[k] = fmaf(pp[k], bf2f(en_bf[(size_t)ee[k] * 64 + lane]), se4[k]);
    }
  }
  for (; i < deg; ++i) {
    float pi = __shfl(p, i, 64);
    int ei = __shfl(e, i, 64);
    int oi = __shfl(oe, i, 64);
    sx4[0] = fmaf(pi, bf2f(x_bf[(size_t)oi * 64 + lane]), sx4[0]);
    se4[0] = fmaf(pi, bf2f(en_bf[(size_t)ei * 64 + lane]), se4[0]);
  }
  float sx = (sx4[0] + sx4[1]) + (sx4[2] + sx4[3]);
  float se = (se4[0] + se4[1]) + (se4[2] + se4[3]);
  float inv = 1.f / (S + 1e-16f);
  ssd[lane] = f2bf(sx * inv);
  ssd[64 + lane] = f2bf(se * inv);
  if (lane == 0) gam[n] = S * inv;
}

// ---- node MLP via MFMA: A-rows read directly as bf16 (x_bf | ss_s | ss_r) ----
__global__ void __launch_bounds__(256) k_node4(
    const unsigned short* __restrict__ x_bf,
    const unsigned short* __restrict__ ss_s, const unsigned short* __restrict__ ss_r,
    const float* __restrict__ gam_s, const float* __restrict__ gam_r,
    const unsigned short* __restrict__ BpN,
    const float* __restrict__ bn, const float* __restrict__ cs, const float* __restrict__ cr,
    const float* __restrict__ pun, const int* __restrict__ nbat,
    float* __restrict__ x_out, int N) {
  __shared__ unsigned short lB[2560 * 8];   // 40KB
  const int tid = threadIdx.x;
  for (int i = tid; i < 2560; i += 256)
    *(uint4*)(lB + (size_t)i * 8) = *(const uint4*)(BpN + (size_t)i * 8);
  __syncthreads();
  const int lane = tid & 63, wid = tid >> 6, l15 = lane & 15, lg = lane >> 4;
  const int n0 = (blockIdx.x * 4 + wid) * 16;
  if (n0 >= N) return;
  int arow = n0 + l15; if (arow >= N) arow = N - 1;

  f32x4 acc[4];
  #pragma unroll
  for (int nt = 0; nt < 4; ++nt) acc[nt] = (f32x4){0.f, 0.f, 0.f, 0.f};

  #pragma unroll
  for (int ks = 0; ks < 10; ++ks) {
    const unsigned short* s;
    if (ks < 2)      s = x_bf + (size_t)arow * 64  + ks * 32 + lg * 8;
    else if (ks < 6) s = ss_s + (size_t)arow * 128 + (ks - 2) * 32 + lg * 8;
    else             s = ss_r + (size_t)arow * 128 + (ks - 6) * 32 + lg * 8;
    bf16x8 A = *(const bf16x8*)s;
    #pragma unroll
    for (int nt = 0; nt < 4; ++nt)
      acc[nt] = MFMA16(A, *(const bf16x8*)(lB + ((size_t)(ks * 4 + nt) * 64 + lane) * 8), acc[nt]);
  }

  #pragma unroll
  for (int j = 0; j < 4; ++j) {
    int n = n0 + lg * 4 + j;
    int nn = n < N ? n : N - 1;
    int g = nbat[nn];
    float gs = gam_s[nn], gr = gam_r[nn];
    #pragma unroll
    for (int nt = 0; nt < 4; ++nt) {
      int o = nt * 16 + l15;
      float v = acc[nt][j] + bn[o] + pun[(size_t)g * 64 + o] + gs * cs[o] + gr * cr[o];
      v = fmaxf(v, 0.f);
      if (n < N) x_out[(size_t)n * 64 + o] = v;
    }
  }
}

// ---- segment-sum f32 (sorted ids, run-length + atomic flush), CHUNK=64 ----
__global__ void __launch_bounds__(256) k_segsum(
    const float* __restrict__ vals, const int* __restrict__ seg,
    float* __restrict__ out, int n) {
  int d = threadIdx.x & 63;
  int grp = threadIdx.x >> 6;
  long base = (long)blockIdx.x * 256 + (long)grp * 64;
  float sum = 0.f;
  int cur = -1;
  for (int k = 0; k < 64; ++k) {
    long e = base + k;
    if (e >= n) break;
    int gb = seg[e];
    float v = vals[e * 64 + d];
    if (gb != cur) {
      if (cur >= 0) atomicAdd(out + (size_t)cur * 64 + d, sum);
      cur = gb; sum = v;
    } else {
      sum += v;
    }
  }
  if (cur >= 0) atomicAdd(out + (size_t)cur * 64 + d, sum);
}

// ---- segment-sum bf16 input, CHUNK=64 ----
__global__ void __launch_bounds__(256) k_segsum_bf(
    const unsigned short* __restrict__ vals, const int* __restrict__ seg,
    float* __restrict__ out, int n) {
  int d = threadIdx.x & 63;
  int grp = threadIdx.x >> 6;
  long base = (long)blockIdx.x * 256 + (long)grp * 64;
  float sum = 0.f;
  int cur = -1;
  for (int k = 0; k < 64; ++k) {
    long e = base + k;
    if (e >= n) break;
    int gb = seg[e];
    float v = bf2f(vals[e * 64 + d]);
    if (gb != cur) {
      if (cur >= 0) atomicAdd(out + (size_t)cur * 64 + d, sum);
      cur = gb; sum = v;
    } else {
      sum += v;
    }
  }
  if (cur >= 0) atomicAdd(out + (size_t)cur * 64 + d, sum);
}

// ---- global MLP ----
__global__ void __launch_bounds__(64) k_glob(
    const float* __restrict__ u, const float* __restrict__ nagg, const float* __restrict__ eagg,
    const float* __restrict__ Wg, const float* __restrict__ bg,
    float* __restrict__ u_out, int G) {
  int t = blockIdx.x * 64 + threadIdx.x;
  if (t >= G * 64) return;
  int g = t >> 6, o = t & 63;
  float acc = bg[o];
  const float* wr = Wg + (size_t)o * 192;
  for (int i = 0; i < 64; ++i) acc = fmaf(u[g * 64 + i],    wr[i],       acc);
  for (int i = 0; i < 64; ++i) acc = fmaf(nagg[g * 64 + i], wr[64 + i],  acc);
  for (int i = 0; i < 64; ++i) acc = fmaf(eagg[g * 64 + i], wr[128 + i], acc);
  u_out[t] = fmaxf(acc, 0.f);
}

extern "C" void kernel_launch(void* const* d_in, const int* in_sizes, int n_in,
                              void* d_out, int out_size, void* d_ws, size_t ws_size,
                              hipStream_t stream) {
  const float* x   = (const float*)d_in[0];
  const float* ea  = (const float*)d_in[1];
  const float* u   = (const float*)d_in[2];
  const float* We  = (const float*)d_in[3];
  const float* be  = (const float*)d_in[4];
  const float* Wn  = (const float*)d_in[5];
  const float* bn  = (const float*)d_in[6];
  const float* Wg  = (const float*)d_in[7];
  const float* bg  = (const float*)d_in[8];
  const float* W1  = (const float*)d_in[9];
  const float* b1  = (const float*)d_in[10];
  const float* w2  = (const float*)d_in[11];
  const float* W3  = (const float*)d_in[12];
  const float* b3  = (const float*)d_in[13];
  const int* eidx  = (const int*)d_in[14];
  const int* nbat  = (const int*)d_in[15];
  const int* ebat  = (const int*)d_in[16];

  const int N = in_sizes[0] / 64;
  const int E = in_sizes[1] / 64;
  const int G = in_sizes[2] / 64;
  const int* row = eidx;
  const int* col = eidx + E;

  float* out   = (float*)d_out;
  float* x_out = out;
  float* e_out = out + (size_t)N * 64;
  float* u_out = out + (size_t)(N + E) * 64;

  // ---- workspace layout (float units) ----
  float* ws = (float*)d_ws;
  uint2* phq = (uint2*)ws;                                   // N*64 uint2 (= N*128 floats)
  // after k_edgeattn5, phq region is dead -> reuse for bf16 ss arrays
  unsigned short* ss_s = (unsigned short*)ws;                // N*128 ushort
  unsigned short* ss_r = (unsigned short*)(ws + (size_t)N * 64);  // N*128 ushort
  unsigned short* x_bf = (unsigned short*)(ws + (size_t)N * 128); // N*64 ushort
  float* w_s = (float*)(x_bf + (size_t)N * 64);              // E
  float* w_r = w_s + E;                                      // E
  float* pu  = w_r + E;                                      // G*64
  float* pun = pu + (size_t)G * 64;                          // G*64
  int* lst_s = (int*)(pun + (size_t)G * 64);                 // N*64
  int* lst_r = lst_s + (size_t)N * 64;                       // N*64
  int* deg_s = lst_r + (size_t)N * 64;                       // N   (memset from here...)
  int* deg_r = deg_s + N;                                    // N
  float* nagg = (float*)(deg_r + N);                         // G*64
  float* eagg = nagg + (size_t)G * 64;                       // G*64 (...to here)
  float* gam_s = eagg + (size_t)G * 64;                      // N
  float* gam_r = gam_s + N;                                  // N
  float* Ms = gam_r + N;                                     // 64*128
  float* Mr = Ms + 64 * 128;                                 // 64*128
  float* cs = Mr + 64 * 128;                                 // 64
  float* cr = cs + 64;                                       // 64
  unsigned short* BpP = (unsigned short*)(cr + 64);          // 2048*8 ushort
  unsigned short* BpN = BpP + 2048 * 8;                      // 2560*8 ushort
  unsigned short* en_bf = BpN + 2560 * 8;                    // E*64 ushort

  hipMemsetAsync(deg_s, 0, (2 * (size_t)N + 2 * (size_t)G * 64) * sizeof(int), stream);

  const int gE = (E + 255) / 256;
  const int gT = (N / 16 + 3) / 4;   // MFMA node-tile blocks (4 waves x 16 nodes)

  k_fill<<<gE, 256, 0, stream>>>(row, col, deg_s, deg_r, lst_s, lst_r, E);
  k_precomb<<<10, 128, 0, stream>>>(Wn, W3, b3, We, u, Ms, cs, Mr, cr, pu, pun, G);
  k_pack<<<18, 256, 0, stream>>>(We, W1, Wn, Ms, Mr, BpP, BpN);
  k_nodepre5<<<gT, 256, 0, stream>>>(x, BpP, phq, x_bf, N);
  k_edgeattn5<<<2048, 256, 0, stream>>>(ea, phq, pu, We, be, W1, b1, w2,
                                        row, col, ebat, e_out, en_bf, w_s, w_r, E);
  k_segsum_bf<<<(E + 255) / 256, 256, 0, stream>>>(en_bf, ebat, eagg, E);
  // gather overwrites phq region (dead after k_edgeattn5)
  k_gatherw2<<<dim3((N + 3) / 4, 2), 256, 0, stream>>>(
      x_bf, en_bf, w_s, w_r, lst_s, lst_r, deg_s, deg_r, row, col,
      ss_s, ss_r, gam_s, gam_r, N);
  k_node4<<<gT, 256, 0, stream>>>(x_bf, ss_s, ss_r, gam_s, gam_r, BpN, bn, cs, cr,
                                  pun, nbat, x_out, N);
  k_segsum<<<(N + 255) / 256, 256, 0, stream>>>(x_out, nbat, nagg, N);
  k_glob<<<(G * 64 + 63) / 64, 64, 0, stream>>>(u, nagg, eagg, Wg, bg, u_out, G);
}